// Round 13
// baseline (211.390 us; speedup 1.0000x reference)
//
#include <hip/hip_runtime.h>
#include <hip/hip_bf16.h>
#include <stdint.h>

#define MROWS 16384   // B*S
#define KDIM  2048
#define NDIM  2048
#define LEAFD 13
#define RANKD 4

typedef __bf16 bf16x8 __attribute__((ext_vector_type(8)));
typedef float  f32x4  __attribute__((ext_vector_type(4)));

// ---------------------------------------------------------------------------
// Kernel 1: w_bf[o,i] = bf16( weight[o,i] + sum_r L0[r,o2,i2]*L1[r,o1,i1]*L2[r,o0,i0] )
// ---------------------------------------------------------------------------
__global__ void build_w_kernel(const float* __restrict__ weight,
                               const float* __restrict__ leaf,
                               __hip_bfloat16* __restrict__ wbf) {
    __shared__ float ll[3 * RANKD * LEAFD * LEAFD];
    for (int t = threadIdx.x; t < 3 * RANKD * LEAFD * LEAFD; t += blockDim.x)
        ll[t] = leaf[t];
    __syncthreads();
    int idx = blockIdx.x * blockDim.x + threadIdx.x;
    if (idx >= NDIM * KDIM) return;
    int o = idx / KDIM, i = idx % KDIM;
    int o2 = o / 169, o1 = (o / 13) % 13, o0 = o % 13;
    int i2 = i / 169, i1 = (i / 13) % 13, i0 = i % 13;
    float d = 0.f;
#pragma unroll
    for (int r = 0; r < RANKD; ++r) {
        float a = ll[( r            * LEAFD + o2) * LEAFD + i2];
        float b = ll[((RANKD   + r) * LEAFD + o1) * LEAFD + i1];
        float c = ll[((2*RANKD + r) * LEAFD + o0) * LEAFD + i0];
        d += a * b * c;
    }
    wbf[idx] = __float2bfloat16(weight[idx] + d);
}

// ---------------------------------------------------------------------------
// Kernel 2: fp32 -> bf16 conversion of activations (8 floats/thread)
// ---------------------------------------------------------------------------
__global__ void cvt_kernel(const float* __restrict__ x,
                           __hip_bfloat16* __restrict__ xb, int n) {
    long stride = (long)gridDim.x * blockDim.x * 8;
    for (long idx = ((long)blockIdx.x * blockDim.x + threadIdx.x) * 8; idx < n; idx += stride) {
        float4 v0 = *reinterpret_cast<const float4*>(x + idx);
        float4 v1 = *reinterpret_cast<const float4*>(x + idx + 4);
        __hip_bfloat16 tmp[8];
        tmp[0] = __float2bfloat16(v0.x); tmp[1] = __float2bfloat16(v0.y);
        tmp[2] = __float2bfloat16(v0.z); tmp[3] = __float2bfloat16(v0.w);
        tmp[4] = __float2bfloat16(v1.x); tmp[5] = __float2bfloat16(v1.y);
        tmp[6] = __float2bfloat16(v1.z); tmp[7] = __float2bfloat16(v1.w);
        *reinterpret_cast<uint4*>(xb + idx) = *reinterpret_cast<const uint4*>(tmp);
    }
}

// ---------------------------------------------------------------------------
// Kernel 3: de-pinned, read-balanced 8-phase GEMM. 256x256 tile, BK=64,
// 16x16x32 MFMA, 8 waves (2M x 4N), per-wave 128x64.
// Window p = { reads(p+1 needs); 1 staging unit (2 gloads); [vmcnt fence];
//              s_barrier; 16 MFMA }.  NO sched_barrier / lgkmcnt(0) asm —
// compiler emits counted lgkm waits and interleaves reads with MFMAs.
// Reads/window: p1:8(A.b0) p2:4(B.q1) p3:8(A.b1) p4:4(B-next.q0, post-fence)
//               p5:8 p6:4 p7:8 p8:4(post-fence).
// Staging (1 unit = half-tile = 2 gloads):
//   p1: B(T+1)h1->buf1   p2,p3: A(T+1)->buf1   p4,p5: B(T+2)->buf0
//   p6,p7: A(T+2)->buf0  p8: B(T+3)h0->buf1
// All slot overwrites >=2 windows after last read (single-barrier-safe).
// Fences: vmcnt(2) at p4 and p8 (keep only that window's unit outstanding).
// Swizzle: involution swz(p)=p^((p>>3)&7) on 16B chunks per 16KB half-tile
// (R2 map: measured 0 conflicts).
// ---------------------------------------------------------------------------

__device__ __forceinline__ void gload16(const __hip_bfloat16* g, char* l) {
    __builtin_amdgcn_global_load_lds((const __attribute__((address_space(1))) void*)g,
                                     (__attribute__((address_space(3))) void*)l,
                                     16, 0, 0);
}

#define STAGE_A(kt, h, BUF) do {                                                        \
    gload16(Abase + (size_t)((h)*128)*KDIM + (kt)*64 + gOff0,                           \
            smemc + (BUF)*65536 + (h)*16384 + sOff0);                                   \
    gload16(Abase + (size_t)((h)*128)*KDIM + (kt)*64 + gOff1,                           \
            smemc + (BUF)*65536 + (h)*16384 + sOff1);                                   \
} while (0)
#define STAGE_B(kt, h, BUF) do {                                                        \
    gload16(Bbase + (size_t)((h)*128)*KDIM + (kt)*64 + gOff0,                           \
            smemc + (BUF)*65536 + 32768 + (h)*16384 + sOff0);                           \
    gload16(Bbase + (size_t)((h)*128)*KDIM + (kt)*64 + gOff1,                           \
            smemc + (BUF)*65536 + 32768 + (h)*16384 + sOff1);                           \
} while (0)

#define RD(off) (*(const bf16x8*)(smemc + (off)))

#define RD_A(BUF, qm) do {                                                              \
    a00 = RD((BUF)*65536 + (qm)*8192 + offA0);                                          \
    a01 = RD((BUF)*65536 + (qm)*8192 + (offA0 ^ 64));                                   \
    a10 = RD((BUF)*65536 + (qm)*8192 + offA1);                                          \
    a11 = RD((BUF)*65536 + (qm)*8192 + (offA1 ^ 64));                                   \
    a20 = RD((BUF)*65536 + (qm)*8192 + offA2);                                          \
    a21 = RD((BUF)*65536 + (qm)*8192 + (offA2 ^ 64));                                   \
    a30 = RD((BUF)*65536 + (qm)*8192 + offA3);                                          \
    a31 = RD((BUF)*65536 + (qm)*8192 + (offA3 ^ 64));                                   \
} while (0)

// B.q0 double-buffered reg sets: Y read @p8/prologue (used p1,p3),
//                                X read @p4 (used p5,p7).
#define RD_B0Y(BUF) do {                                                                \
    by00 = RD((BUF)*65536 + offB0);        by01 = RD((BUF)*65536 + (offB0 ^ 64));       \
    by10 = RD((BUF)*65536 + offB1);        by11 = RD((BUF)*65536 + (offB1 ^ 64));       \
} while (0)
#define RD_B0X(BUF) do {                                                                \
    bx00 = RD((BUF)*65536 + offB0);        bx01 = RD((BUF)*65536 + (offB0 ^ 64));       \
    bx10 = RD((BUF)*65536 + offB1);        bx11 = RD((BUF)*65536 + (offB1 ^ 64));       \
} while (0)
#define RD_B1(BUF) do {                                                                 \
    bq00 = RD((BUF)*65536 + 4096 + offB0); bq01 = RD((BUF)*65536 + 4096 + (offB0 ^ 64)); \
    bq10 = RD((BUF)*65536 + 4096 + offB1); bq11 = RD((BUF)*65536 + 4096 + (offB1 ^ 64)); \
} while (0)

// One quadrant x K=64: 16 MFMA.
#define MFMA_QD(qm, B00,B01,B10,B11, N0, N1) do {                                               \
    acc[(qm)*4+0][N0] = __builtin_amdgcn_mfma_f32_16x16x32_bf16(a00, B00, acc[(qm)*4+0][N0],0,0,0); \
    acc[(qm)*4+1][N0] = __builtin_amdgcn_mfma_f32_16x16x32_bf16(a10, B00, acc[(qm)*4+1][N0],0,0,0); \
    acc[(qm)*4+2][N0] = __builtin_amdgcn_mfma_f32_16x16x32_bf16(a20, B00, acc[(qm)*4+2][N0],0,0,0); \
    acc[(qm)*4+3][N0] = __builtin_amdgcn_mfma_f32_16x16x32_bf16(a30, B00, acc[(qm)*4+3][N0],0,0,0); \
    acc[(qm)*4+0][N1] = __builtin_amdgcn_mfma_f32_16x16x32_bf16(a00, B10, acc[(qm)*4+0][N1],0,0,0); \
    acc[(qm)*4+1][N1] = __builtin_amdgcn_mfma_f32_16x16x32_bf16(a10, B10, acc[(qm)*4+1][N1],0,0,0); \
    acc[(qm)*4+2][N1] = __builtin_amdgcn_mfma_f32_16x16x32_bf16(a20, B10, acc[(qm)*4+2][N1],0,0,0); \
    acc[(qm)*4+3][N1] = __builtin_amdgcn_mfma_f32_16x16x32_bf16(a30, B10, acc[(qm)*4+3][N1],0,0,0); \
    acc[(qm)*4+0][N0] = __builtin_amdgcn_mfma_f32_16x16x32_bf16(a01, B01, acc[(qm)*4+0][N0],0,0,0); \
    acc[(qm)*4+1][N0] = __builtin_amdgcn_mfma_f32_16x16x32_bf16(a11, B01, acc[(qm)*4+1][N0],0,0,0); \
    acc[(qm)*4+2][N0] = __builtin_amdgcn_mfma_f32_16x16x32_bf16(a21, B01, acc[(qm)*4+2][N0],0,0,0); \
    acc[(qm)*4+3][N0] = __builtin_amdgcn_mfma_f32_16x16x32_bf16(a31, B01, acc[(qm)*4+3][N0],0,0,0); \
    acc[(qm)*4+0][N1] = __builtin_amdgcn_mfma_f32_16x16x32_bf16(a01, B11, acc[(qm)*4+0][N1],0,0,0); \
    acc[(qm)*4+1][N1] = __builtin_amdgcn_mfma_f32_16x16x32_bf16(a11, B11, acc[(qm)*4+1][N1],0,0,0); \
    acc[(qm)*4+2][N1] = __builtin_amdgcn_mfma_f32_16x16x32_bf16(a21, B11, acc[(qm)*4+2][N1],0,0,0); \
    acc[(qm)*4+3][N1] = __builtin_amdgcn_mfma_f32_16x16x32_bf16(a31, B11, acc[(qm)*4+3][N1],0,0,0); \
} while (0)

#define BAR __builtin_amdgcn_s_barrier()
#define F2  asm volatile("s_waitcnt vmcnt(2)" ::: "memory")
#define FD0 asm volatile("s_waitcnt vmcnt(0)" ::: "memory")
#define FW8 asm volatile("s_waitcnt vmcnt(8)" ::: "memory")
#define FNONE do {} while (0)

// One iteration: tiles T (buf0, p1-p4) and T+1 (buf1, p5-p8).
// Flags: PS1 (B(T+1)h1), PS23 (A(T+1)), PS45 (B(T+2)), PS67 (A(T+2)),
//        PS8 (B(T+3)h0), RP8 (post-fence read of B(T+2).q0).
#define KITER(T, PS1, PS23, PS45, PS67, PS8, F4_, F8_, RP8) do {    \
    /* p1 */                                                        \
    RD_A(0, 0);                                                     \
    if (PS1)  STAGE_B((T)+1, 1, 1);                                 \
    BAR;                                                            \
    MFMA_QD(0, by00,by01,by10,by11, 0,1);                           \
    /* p2 */                                                        \
    RD_B1(0);                                                       \
    if (PS23) STAGE_A((T)+1, 0, 1);                                 \
    BAR;                                                            \
    MFMA_QD(0, bq00,bq01,bq10,bq11, 2,3);                           \
    /* p3 */                                                        \
    RD_A(0, 1);                                                     \
    if (PS23) STAGE_A((T)+1, 1, 1);                                 \
    BAR;                                                            \
    MFMA_QD(1, by00,by01,by10,by11, 0,1);                           \
    /* p4 */                                                        \
    if (PS45) STAGE_B((T)+2, 0, 0);                                 \
    F4_;                                                            \
    RD_B0X(1);                                                      \
    BAR;                                                            \
    MFMA_QD(1, bq00,bq01,bq10,bq11, 2,3);                           \
    /* p5 */                                                        \
    RD_A(1, 0);                                                     \
    if (PS45) STAGE_B((T)+2, 1, 0);                                 \
    BAR;                                                            \
    MFMA_QD(0, bx00,bx01,bx10,bx11, 0,1);                           \
    /* p6 */                                                        \
    RD_B1(1);                                                       \
    if (PS67) STAGE_A((T)+2, 0, 0);                                 \
    BAR;                                                            \
    MFMA_QD(0, bq00,bq01,bq10,bq11, 2,3);                           \
    /* p7 */                                                        \
    RD_A(1, 1);                                                     \
    if (PS67) STAGE_A((T)+2, 1, 0);                                 \
    BAR;                                                            \
    MFMA_QD(1, bx00,bx01,bx10,bx11, 0,1);                           \
    /* p8 */                                                        \
    if (PS8)  STAGE_B((T)+3, 0, 1);                                 \
    F8_;                                                            \
    if (RP8)  RD_B0Y(0);                                            \
    BAR;                                                            \
    MFMA_QD(1, bq00,bq01,bq10,bq11, 2,3);                           \
} while (0)

__global__ __launch_bounds__(512, 1) void gemm9_kernel(const __hip_bfloat16* __restrict__ A,
                                                       const __hip_bfloat16* __restrict__ Wb,
                                                       const float* __restrict__ bias,
                                                       float* __restrict__ C) {
    __shared__ __align__(16) char smem_raw[2 * 65536];   // 128 KiB
    char* smemc = smem_raw;

    const int tid  = threadIdx.x;
    const int lane = tid & 63;
    const int wid  = tid >> 6;        // 0..7
    const int wr   = wid >> 2;        // 0..1  (M half)
    const int wc   = wid & 3;         // 0..3  (N quarter)

    // T1: XCD-aware swizzle (nwg=512, 512%8==0 -> bijective).
    const int bid = blockIdx.x;
    const int swz = (bid & 7) * 64 + (bid >> 3);
    const int bn  = swz >> 6;         // 0..7
    const int bm  = swz & 63;         // 0..63

    const __hip_bfloat16* Abase = A  + (size_t)bm * 256 * KDIM;
    const __hip_bfloat16* Bbase = Wb + (size_t)bn * 256 * KDIM;

    // --- staging source (inverse involution on 16B chunks of a 16KB half) ---
    int gOff0, gOff1;
    {
        const int c0 = wid * 128 + lane;
        const int c1 = c0 + 64;
        const int s0 = c0 ^ ((c0 >> 3) & 7);
        const int s1 = c1 ^ ((c1 >> 3) & 7);
        gOff0 = (s0 >> 3) * KDIM + (s0 & 7) * 8;
        gOff1 = (s1 >> 3) * KDIM + (s1 & 7) * 8;
    }
    const int sOff0 = wid * 2048;          // bytes (wave-uniform)
    const int sOff1 = wid * 2048 + 1024;

    // --- fragment read base offsets (qm=0,qn=0,ks=0); ks->^64, qm->+8192,
    //     qn->+4096 ---
    const int rsel = lane & 15;
    const int kq   = lane >> 4;            // 0..3
    int offA0, offA1, offA2, offA3, offB0, offB1;
    {
        const int abase = wr * 16384;
#pragma unroll
        for (int mf = 0; mf < 4; ++mf) {
            const int row = mf * 16 + rsel;
            const int off = abase + row * 128 + (kq ^ (row & 7)) * 16;
            if (mf == 0) offA0 = off; else if (mf == 1) offA1 = off;
            else if (mf == 2) offA2 = off; else offA3 = off;
        }
        const int bbase = 32768 + (wc >> 1) * 16384;
#pragma unroll
        for (int nf = 0; nf < 2; ++nf) {
            const int row = (wc & 1) * 64 + nf * 16 + rsel;
            const int off = bbase + row * 128 + (kq ^ (row & 7)) * 16;
            if (nf == 0) offB0 = off; else offB1 = off;
        }
    }

    f32x4 acc[8][4];
#pragma unroll
    for (int m = 0; m < 8; ++m)
#pragma unroll
        for (int n = 0; n < 4; ++n)
            acc[m][n] = (f32x4){0.f, 0.f, 0.f, 0.f};

    bf16x8 a00, a01, a10, a11, a20, a21, a30, a31;
    bf16x8 by00, by01, by10, by11;     // B.q0 set Y (read p8/prologue, used p1,p3)
    bf16x8 bx00, bx01, bx10, bx11;     // B.q0 set X (read p4, used p5,p7)
    bf16x8 bq00, bq01, bq10, bq11;     // B.q1 (read p2/p6, used p2,p4 / p6,p8)

    // --- prologue: stage t0 -> buf0, t1 -> buf1 (16 gloads/wave) ---
    STAGE_A(0, 0, 0); STAGE_A(0, 1, 0); STAGE_B(0, 0, 0); STAGE_B(0, 1, 0);
    STAGE_A(1, 0, 1); STAGE_A(1, 1, 1); STAGE_B(1, 0, 1); STAGE_B(1, 1, 1);
    FW8;                    // t0 landed; t1's 8 loads may stay in flight
    BAR;
    RD_B0Y(0);              // B(0).q0 (compiler-counted drain at first use)

    // --- main loop: 32 K-tiles = 16 iterations ---
    KITER(0, 0, 0, 1, 1, 1, F2, F2, 1);       // i=0: t1 staged in prologue
    for (int i = 1; i < 15; ++i) {
        KITER(2 * i, 1, 1, 1, 1, 1, F2, F2, 1);
    }
    KITER(30, 1, 1, 0, 0, 0, FD0, FNONE, 0);  // i=15: drain; no t32+ staging

    // --- epilogue: C/D layout col = lane&15, row = (lane>>4)*4 + r ---
    const int col0 = rsel;
    const int r0   = kq * 4;
#pragma unroll
    for (int n = 0; n < 4; ++n) {
        const int cg = bn * 256 + wc * 64 + n * 16 + col0;
        const float bv = bias[cg];
#pragma unroll
        for (int m = 0; m < 8; ++m) {
            const size_t rg = (size_t)bm * 256 + wr * 128 + m * 16 + r0;
#pragma unroll
            for (int r = 0; r < 4; ++r)
                C[(rg + r) * NDIM + cg] = acc[m][n][r] + bv;
        }
    }
}

// ---------------------------------------------------------------------------
// Fallback: naive fused fp32 GEMM (only if workspace too small).
// ---------------------------------------------------------------------------
__global__ void naive_kernel(const float* __restrict__ x,
                             const float* __restrict__ leaf,
                             const float* __restrict__ W,
                             const float* __restrict__ bias,
                             float* __restrict__ out) {
    long idx = (long)blockIdx.x * blockDim.x + threadIdx.x;
    if (idx >= (long)MROWS * NDIM) return;
    int  o = (int)(idx % NDIM);
    long m = idx / NDIM;
    int o2 = o / 169, o1 = (o / 13) % 13, o0 = o % 13;
    float acc = 0.f;
    for (int i = 0; i < KDIM; ++i) {
        int i2 = i / 169, i1 = (i / 13) % 13, i0 = i % 13;
        float d = 0.f;
#pragma unroll
        for (int r = 0; r < RANKD; ++r)
            d += leaf[( r     * LEAFD + o2) * LEAFD + i2]
               * leaf[((4 + r) * LEAFD + o1) * LEAFD + i1]
               * leaf[((8 + r) * LEAFD + o0) * LEAFD + i0];
        acc += x[m * KDIM + i] * (W[(long)o * KDIM + i] + d);
    }
    out[idx] = acc + bias[o];
}

// ---------------------------------------------------------------------------
extern "C" void kernel_launch(void* const* d_in, const int* in_sizes, int n_in,
                              void* d_out, int out_size, void* d_ws, size_t ws_size,
                              hipStream_t stream) {
    const float* x      = (const float*)d_in[0];
    const float* leaf   = (const float*)d_in[1];
    const float* weight = (const float*)d_in[2];
    const float* bias   = (const float*)d_in[3];
    float* out = (float*)d_out;

    const size_t needA = (size_t)MROWS * KDIM * sizeof(__hip_bfloat16);  // 64 MiB
    const size_t needW = (size_t)NDIM  * KDIM * sizeof(__hip_bfloat16);  // 8 MiB

    if (ws_size >= needA + needW) {
        __hip_bfloat16* xb = (__hip_bfloat16*)d_ws;
        __hip_bfloat16* wb = (__hip_bfloat16*)((char*)d_ws + needA);
        build_w_kernel<<<(NDIM * KDIM + 255) / 256, 256, 0, stream>>>(weight, leaf, wb);
        cvt_kernel<<<2048, 256, 0, stream>>>(x, xb, MROWS * KDIM);
        gemm9_kernel<<<(MROWS / 256) * (NDIM / 256), 512, 0, stream>>>(xb, wb, bias, out);
    } else {
        long total = (long)MROWS * NDIM;
        naive_kernel<<<(int)((total + 255) / 256), 256, 0, stream>>>(x, leaf, weight, bias, out);
    }
}